// Round 4
// baseline (973.779 us; speedup 1.0000x reference)
//
#include <hip/hip_runtime.h>
#include <stdint.h>

typedef unsigned short u16;
typedef __bf16 bf16x8 __attribute__((ext_vector_type(8)));
typedef float  f32x4  __attribute__((ext_vector_type(4)));
typedef float  f32x16 __attribute__((ext_vector_type(16)));

#define D_MODEL 2048
#define SEQ     4096
#define NROWS   16384     // B*S = 4*4096
#define THREE_D 6144
#define K_SIZE  4
#define KC      2048      // GEMM K (both GEMMs)
#define NT      64        // K-steps of 32

__device__ __forceinline__ float b2f(u16 u) {
    union { uint32_t i; float f; } v; v.i = ((uint32_t)u) << 16; return v.f;
}
__device__ __forceinline__ u16 f2b(float f) {
    uint32_t u = __builtin_bit_cast(uint32_t, f);
    u += 0x7fff + ((u >> 16) & 1);          // RNE
    return (u16)(u >> 16);
}

// ---------------- fp32 -> bf16 cast (8 elems/thread) ----------------
__global__ __launch_bounds__(256) void cast_f32_to_bf16(
    const float* __restrict__ src, u16* __restrict__ dst, int n8)
{
    int i = blockIdx.x * blockDim.x + threadIdx.x;
    if (i >= n8) return;
    const float4* s = (const float4*)src + (size_t)i * 2;
    float4 a = s[0], b = s[1];
    union { u16 u[8]; uint4 v; } o;
    o.u[0] = f2b(a.x); o.u[1] = f2b(a.y); o.u[2] = f2b(a.z); o.u[3] = f2b(a.w);
    o.u[4] = f2b(b.x); o.u[5] = f2b(b.y); o.u[6] = f2b(b.z); o.u[7] = f2b(b.w);
    *(uint4*)(dst + (size_t)i * 8) = o.v;
}

// ---------------- conv_w [D,1,K] -> cwt [K,D] transpose ----------------
__global__ __launch_bounds__(256) void prep_cwt(
    const float* __restrict__ cw, float* __restrict__ cwt)
{
    int i = blockIdx.x * blockDim.x + threadIdx.x;
    if (i >= D_MODEL * K_SIZE) return;
    int d = i >> 2, k = i & 3;
    cwt[k * D_MODEL + d] = cw[i];
}

#define GLDS(gp, lp) __builtin_amdgcn_global_load_lds( \
    (const __attribute__((address_space(1))) void*)(gp), \
    (__attribute__((address_space(3))) void*)(lp), 16, 0, 0)

// ---------------- bf16 NT GEMM: C[M,N] = A[M,K] * B[N,K]^T ----------------
// FAT-WAVE design: 256x256 tile, 256 threads = 4 waves (1/SIMD), each wave a
// 128x128 output = 4x4 tiles of 32x32, acc = 4x4 f32x16 (256 AGPR). The
// 1-wave/SIMD regime frees the register budget (512 unified) to FULLY
// double-buffer operand fragments (2 x 16 b128 = 128 VGPR), which no
// 2-wave/SIMD config can afford — this is what makes true software
// pipelining possible (rounds 1-2 failed on this wall at 8 waves).
//
// Per K-step (BK=32), ONE barrier + counted waits (T4):
//   vmcnt(8)            -> tile t+1 landed (staged 2 steps ~ 2000 cyc ago)
//   s_barrier           -> all waves' stages landed; read/write edges ordered
//   STAGE(t+3)          -> 8 global_load_lds into ring buf (t+3)&3
//   DSREAD(t+1 -> alt)  -> 16 ds_read_b128 into the idle frag set
//   lgkmcnt(15)         -> prev set done (+oldest new read; 4-bit field max)
//   sched_barrier(0)    -> rule 18: keep MFMA below the wait
//   32 x mfma_f32_32x32x16_bf16 (setprio-wrapped), 2495 TF-ceiling shape
// Race edges (both through the single barrier):
//   - reads(t+1) execute after ALL waves' vmcnt => staged data visible.
//   - STAGE(t+3) overwrites buf[t-1]; its reads were drained by each wave's
//     lgkmcnt in iter t-1, which precedes barrier(t) => write-after-read safe.
// LDS: ring of 4 bufs x 32 KiB (A 16K | B 16K) = 128 KiB. Fragment-major
// chunk (g,q,fr) at u16 off g*512+q*128+fr*8 (row g*16+fr, k q*8..+7):
// staging dest is exactly tid*16B (lane-linear, rule 21) and ds_read_b128
// covers 64 distinct 16B slots -> conflict-free (PMC-verified 0 in r1/r2).
template<int BF16OUT>
__global__ __launch_bounds__(256, 1) void gemm_fat(
    const u16* __restrict__ A, const u16* __restrict__ B,
    void* __restrict__ Cout, int N, int n_per_xcd)
{
    __shared__ __align__(16) u16 lds[65536];   // 128 KiB

    const int tid  = threadIdx.x;
    const int lane = tid & 63;
    const int wv   = tid >> 6;

    const int idx   = blockIdx.x;
    const int xcd   = idx & 7;
    const int local = idx >> 3;
    const int bm  = local / n_per_xcd;
    const int bn  = xcd * n_per_xcd + (local - bm * n_per_xcd);

    const size_t sK = (size_t)KC;
    // staging: thread stages chunks cid = p*256+tid (p=0..3) of A and of B.
    // cid -> fr=cid&15, q=(cid>>4)&3, g=cid>>6; lds off = cid*8 u16 = p*2048+tid*8
    const int sfr = tid & 15, sq = (tid >> 4) & 3, sg = tid >> 6;
    const u16* Ab = A + ((size_t)(bm * 256) + sg * 16 + sfr) * sK + sq * 8;
    const u16* Bb = B + ((size_t)(bn * 256) + sg * 16 + sfr) * sK + sq * 8;

    // fragment addressing: A row=(wv>>1)*128+mt*32+(lane&31), k=ks*16+(lane>>5)*8
    const int fr  = lane & 15;
    const int rhi = (lane >> 4) & 1;
    const int kh  = lane >> 5;
    const int aoff =        ((wv >> 1) * 8 + rhi) * 512 + kh * 128 + fr * 8; // +mt*1024+ks*256
    const int boff = 8192 + ((wv &  1) * 8 + rhi) * 512 + kh * 128 + fr * 8; // +nt*1024+ks*256

    f32x16 acc[4][4] = {};
    bf16x8 fA[8][2], fB[8][2];   // [0..3] = A(mt), [4..7] = B(nt); [.][ks]

#define STAGE(t_) { const int _t = (t_); if (_t < NT) { \
    const int _kk = _t * 32; \
    u16* _d = lds + (_t & 3) * 16384 + tid * 8; \
    GLDS(Ab + _kk,              _d); \
    GLDS(Ab +  64 * sK + _kk,   _d + 2048); \
    GLDS(Ab + 128 * sK + _kk,   _d + 4096); \
    GLDS(Ab + 192 * sK + _kk,   _d + 6144); \
    GLDS(Bb + _kk,              _d + 8192); \
    GLDS(Bb +  64 * sK + _kk,   _d + 10240); \
    GLDS(Bb + 128 * sK + _kk,   _d + 12288); \
    GLDS(Bb + 192 * sK + _kk,   _d + 14336); } }

#define DSREAD(t_, F) { const u16* _b = lds + ((t_) & 3) * 16384; \
    _Pragma("unroll") for (int i = 0; i < 4; i++) { \
        F[i][0]     = *(const bf16x8*)(_b + aoff + i * 1024); \
        F[i][1]     = *(const bf16x8*)(_b + aoff + i * 1024 + 256); \
        F[i + 4][0] = *(const bf16x8*)(_b + boff + i * 1024); \
        F[i + 4][1] = *(const bf16x8*)(_b + boff + i * 1024 + 256); } }

#define MM(F) { __builtin_amdgcn_s_setprio(1); \
    _Pragma("unroll") for (int mt = 0; mt < 4; mt++) \
    _Pragma("unroll") for (int nt = 0; nt < 4; nt++) { \
        acc[mt][nt] = __builtin_amdgcn_mfma_f32_32x32x16_bf16( \
            F[mt][0], F[nt + 4][0], acc[mt][nt], 0, 0, 0); \
        acc[mt][nt] = __builtin_amdgcn_mfma_f32_32x32x16_bf16( \
            F[mt][1], F[nt + 4][1], acc[mt][nt], 0, 0, 0); } \
    __builtin_amdgcn_s_setprio(0); }

    // ---- prologue: stage 0,1,2; own stage-0 landed; barrier; reads(0) ----
    STAGE(0); STAGE(1); STAGE(2);
    asm volatile("s_waitcnt vmcnt(16)" ::: "memory");
    __builtin_amdgcn_s_barrier();
    DSREAD(0, fA);

    // ---- steady state: uniform vmcnt(8)/lgkmcnt(15), 1 barrier/K-step ----
    for (int t = 0; t < NT - 2; t += 2) {
        asm volatile("s_waitcnt vmcnt(8)" ::: "memory");   // t+1 landed
        __builtin_amdgcn_s_barrier();
        STAGE(t + 3);
        DSREAD(t + 1, fB);
        asm volatile("s_waitcnt lgkmcnt(15)" ::: "memory"); // fA ready
        __builtin_amdgcn_sched_barrier(0);
        MM(fA);

        asm volatile("s_waitcnt vmcnt(8)" ::: "memory");   // t+2 landed
        __builtin_amdgcn_s_barrier();
        STAGE(t + 4);
        DSREAD(t + 2, fA);
        asm volatile("s_waitcnt lgkmcnt(15)" ::: "memory"); // fB ready
        __builtin_amdgcn_sched_barrier(0);
        MM(fB);
    }
    // ---- t = NT-2 ----
    asm volatile("s_waitcnt vmcnt(0)" ::: "memory");       // NT-1 landed
    __builtin_amdgcn_s_barrier();
    DSREAD(NT - 1, fB);
    asm volatile("s_waitcnt lgkmcnt(15)" ::: "memory");
    __builtin_amdgcn_sched_barrier(0);
    MM(fA);
    // ---- t = NT-1 ----
    asm volatile("s_waitcnt lgkmcnt(0)" ::: "memory");
    __builtin_amdgcn_sched_barrier(0);
    MM(fB);

    // ---- epilogue: 32x32 D-map col=lane&31, row=(reg&3)+8*(reg>>2)+4*(lane>>5)
    const int col0 = bn * 256 + (wv & 1) * 128 + (lane & 31);
    const int rb   = bm * 256 + (wv >> 1) * 128 + kh * 4;
    if (BF16OUT) {
        u16* C = (u16*)Cout;
        #pragma unroll
        for (int mt = 0; mt < 4; mt++)
            #pragma unroll
            for (int nt = 0; nt < 4; nt++)
                #pragma unroll
                for (int r = 0; r < 16; r++) {
                    const int row = rb + mt * 32 + (r & 3) + 8 * (r >> 2);
                    C[(size_t)row * N + col0 + nt * 32] = f2b(acc[mt][nt][r]);
                }
    } else {
        float* C = (float*)Cout;
        #pragma unroll
        for (int mt = 0; mt < 4; mt++)
            #pragma unroll
            for (int nt = 0; nt < 4; nt++)
                #pragma unroll
                for (int r = 0; r < 16; r++) {
                    const int row = rb + mt * 32 + (r & 3) + 8 * (r >> 2);
                    C[(size_t)row * N + col0 + nt * 32] = acc[mt][nt][r];
                }
    }
#undef STAGE
#undef DSREAD
#undef MM
}

// ---------------- gate + causal depthwise conv + gate2 ----------------
// z[n,d] = Cg[n,d] * sum_{k=0..3} Bg[n-3+k,d]*Xg[n-3+k,d]*cw[d,k]
// BCx row layout: [Bg(0..2047) | Cg(2048..4095) | Xg(4096..6143)]
__global__ __launch_bounds__(256) void gate_conv(
    const u16* __restrict__ BCx, const float* __restrict__ cwt, u16* __restrict__ z)
{
    const int n  = blockIdx.x;              // 0..16383
    const int dg = threadIdx.x << 3;        // 8 channels per thread
    const int s  = n & (SEQ - 1);
    const u16* base = BCx + (size_t)n * THREE_D;

    float conv[8];
    #pragma unroll
    for (int j = 0; j < 8; j++) conv[j] = 0.f;

    #pragma unroll
    for (int r = 0; r < 4; r++) {           // tap index k = r, source row n-3+r
        const int back = 3 - r;
        if (s >= back) {                    // block-uniform branch
            const u16* pb = base - (size_t)back * THREE_D + dg;
            union { uint4 v; u16 u[8]; } ub, ux;
            ub.v = *(const uint4*)pb;                    // Bg
            ux.v = *(const uint4*)(pb + 2 * D_MODEL);    // Xg
            const float* w = cwt + r * D_MODEL + dg;
            float4 w0 = *(const float4*)w;
            float4 w1 = *(const float4*)(w + 4);
            float ww[8] = { w0.x, w0.y, w0.z, w0.w, w1.x, w1.y, w1.z, w1.w };
            #pragma unroll
            for (int j = 0; j < 8; j++)
                conv[j] += b2f(ub.u[j]) * b2f(ux.u[j]) * ww[j];
        }
    }

    union { uint4 v; u16 u[8]; } uc, uo;
    uc.v = *(const uint4*)(base + D_MODEL + dg);         // Cg
    #pragma unroll
    for (int j = 0; j < 8; j++)
        uo.u[j] = f2b(b2f(uc.u[j]) * conv[j]);
    *(uint4*)(z + (size_t)n * D_MODEL + dg) = uo.v;
}

extern "C" void kernel_launch(void* const* d_in, const int* in_sizes, int n_in,
                              void* d_out, int out_size, void* d_ws, size_t ws_size,
                              hipStream_t stream) {
    const float* x  = (const float*)d_in[0];   // [4,4096,2048]
    const float* w1 = (const float*)d_in[1];   // [6144,2048]
    const float* w2 = (const float*)d_in[2];   // [2048,2048]
    const float* cw = (const float*)d_in[3];   // [2048,1,4]
    float* out = (float*)d_out;                // [4,4096,2048] fp32

    // workspace layout (bytes), all 16B-aligned:
    char* ws = (char*)d_ws;
    u16*   xb  = (u16*)(ws);                       //  64 MiB  bf16 x
    u16*   w1b = (u16*)(ws + 67108864);            //  24 MiB  bf16 w1
    u16*   w2b = (u16*)(ws + 92274688);            //   8 MiB  bf16 w2
    float* cwt = (float*)(ws + 100663296);         //  32 KiB  conv_w transposed [K,D]
    u16*   bcx = (u16*)(ws + 100696064);           // 192 MiB  BCx bf16 [16384,6144]
    u16*   z   = (u16*)(ws + 302022656);           //  64 MiB  z bf16 [16384,2048]

    cast_f32_to_bf16<<<dim3((4194304 + 255) / 256), 256, 0, stream>>>(x,  xb,  4194304);
    cast_f32_to_bf16<<<dim3((1572864 + 255) / 256), 256, 0, stream>>>(w1, w1b, 1572864);
    cast_f32_to_bf16<<<dim3((524288  + 255) / 256), 256, 0, stream>>>(w2, w2b, 524288);
    prep_cwt<<<dim3(32), 256, 0, stream>>>(cw, cwt);

    // GEMM1: BCx = x @ w1^T   [16384,6144]; 64x24 tiles = 1536 blocks (3 N-tiles/XCD)
    gemm_fat<1><<<dim3(1536), 256, 0, stream>>>(xb, w1b, (void*)bcx, THREE_D, 3);
    // gate + conv -> z bf16 [16384,2048]
    gate_conv<<<dim3(NROWS), 256, 0, stream>>>(bcx, cwt, z);
    // GEMM2: out = z @ w2^T   [16384,2048] fp32; 64x8 tiles = 512 blocks (1 N-tile/XCD)
    gemm_fat<0><<<dim3(512), 256, 0, stream>>>(z, w2b, (void*)out, D_MODEL, 1);
}